// Round 4
// baseline (247.144 us; speedup 1.0000x reference)
//
#include <hip/hip_runtime.h>
#include <hip/hip_bf16.h>

// GCN: h1 = relu(Â (x W1) + b1); h2 = relu(Â (h1 W2) + b2);
// out = meanpool_by_graph(h2) @ Wf + bf
// Â = D^-1/2 (A + I) D^-1/2, deg counted on edge TARGETS + self loop.
//
// GEMMs on MFMA via split-bf16 (3× mfma_f32_16x16x32_bf16, fp32 acc);
// GEMM epilogue pre-scales row i by dinv[i].
// Aggregation is dim-sliced XCD-aware: slice s = blockIdx%8 touches only
// h[:, 16s:16s+16] (3.2 MB < 4 MB per-XCD L2) so gathers are L2 hits.

#define D 128

typedef __attribute__((ext_vector_type(8))) short short8;
typedef __attribute__((ext_vector_type(4))) float f32x4;

// byte offset into a K-contiguous LDS tile with 256B rows, XOR-swizzled
__device__ __forceinline__ int swz(int row, int kbyte) {
    return row * 256 + (kbyte ^ ((row & 7) << 4));
}

__device__ __forceinline__ void cvt8(const float* f, uint4& vh, uint4& vl) {
    uint h[8], l[8];
#pragma unroll
    for (int j = 0; j < 8; ++j) {
        uint ub = __float_as_uint(f[j]);
        uint hb = ub & 0xffff0000u;           // truncate to bf16-hi
        float r = f[j] - __uint_as_float(hb); // exact residual
        h[j] = hb >> 16;
        l[j] = __float_as_uint(r) >> 16;
    }
    vh = make_uint4(h[0] | (h[1] << 16), h[2] | (h[3] << 16),
                    h[4] | (h[5] << 16), h[6] | (h[7] << 16));
    vl = make_uint4(l[0] | (l[1] << 16), l[2] | (l[3] << 16),
                    l[4] | (l[5] << 16), l[6] | (l[7] << 16));
}

// ---------- degree count ----------
__global__ void k_deg(const int* __restrict__ col, int* __restrict__ cnt, int E) {
    int e = blockIdx.x * blockDim.x + threadIdx.x;
    if (e < E) atomicAdd(&cnt[col[e]], 1);
}

__global__ void k_dinv(const int* __restrict__ cnt, float* __restrict__ dinv, int n) {
    int i = blockIdx.x * blockDim.x + threadIdx.x;
    if (i < n) dinv[i] = 1.0f / sqrtf((float)(cnt[i] + 1));
}

// ---------- two-level exclusive scan over cnt[n] ----------
__global__ __launch_bounds__(256) void k_scan_partial(const int* __restrict__ cnt,
                                                      int* __restrict__ partial, int n) {
    int t = threadIdx.x;
    int base = blockIdx.x * 1024 + t * 4;
    int s = 0;
#pragma unroll
    for (int j = 0; j < 4; ++j) {
        int i = base + j;
        if (i < n) s += cnt[i];
    }
#pragma unroll
    for (int o = 32; o > 0; o >>= 1) s += __shfl_down(s, o, 64);
    __shared__ int ws[4];
    if ((t & 63) == 0) ws[t >> 6] = s;
    __syncthreads();
    if (t == 0) partial[blockIdx.x] = ws[0] + ws[1] + ws[2] + ws[3];
}

__global__ void k_scan_mid(int* __restrict__ partial, int nb,
                           int* __restrict__ offs, int n) {
    if (threadIdx.x == 0 && blockIdx.x == 0) {
        int run = 0;
        for (int i = 0; i < nb; ++i) { int v = partial[i]; partial[i] = run; run += v; }
        offs[n] = run;
    }
}

__global__ __launch_bounds__(256) void k_scan_final(const int* __restrict__ cnt,
                                                    const int* __restrict__ pprefix,
                                                    int* __restrict__ offs,
                                                    int* __restrict__ cursor, int n) {
    int t = threadIdx.x;
    int lane = t & 63;
    int base = blockIdx.x * 1024 + t * 4;
    int v[4];
    int s = 0;
#pragma unroll
    for (int j = 0; j < 4; ++j) {
        int i = base + j;
        v[j] = (i < n) ? cnt[i] : 0;
        s += v[j];
    }
    int inc = s;
#pragma unroll
    for (int o = 1; o < 64; o <<= 1) {
        int u = __shfl_up(inc, o, 64);
        if (lane >= o) inc += u;
    }
    __shared__ int wsum[4];
    if (lane == 63) wsum[t >> 6] = inc;
    __syncthreads();
    int woff = 0;
    int w = t >> 6;
    for (int k = 0; k < w; ++k) woff += wsum[k];
    int excl = woff + (inc - s) + pprefix[blockIdx.x];
#pragma unroll
    for (int j = 0; j < 4; ++j) {
        int i = base + j;
        if (i < n) { offs[i] = excl; cursor[i] = excl; }
        excl += v[j];
    }
}

// ---------- CSR fill ----------
__global__ void k_fill(const int* __restrict__ ei, int* __restrict__ cursor,
                       int* __restrict__ csr, int E) {
    int e = blockIdx.x * blockDim.x + threadIdx.x;
    if (e < E) {
        int r = ei[e];
        int c = ei[E + e];
        int pos = atomicAdd(&cursor[c], 1);
        csr[pos] = r;
    }
}

// ---------- weight convert+transpose: W[k][n] fp32 -> Wt_hi/lo[n][k] bf16 ----------
__global__ __launch_bounds__(256) void k_wcvt(const float* __restrict__ W,
                                              ushort* __restrict__ Wt_hi,
                                              ushort* __restrict__ Wt_lo) {
    int t = blockIdx.x * 256 + threadIdx.x;   // 2048 items: 128 n-rows × 16 kchunks
    int nrow = t >> 4;
    int kc = t & 15;
    float f[8];
#pragma unroll
    for (int j = 0; j < 8; ++j) f[j] = W[(kc * 8 + j) * D + nrow];
    uint4 vh, vl;
    cvt8(f, vh, vl);
    *(uint4*)&Wt_hi[nrow * D + kc * 8] = vh;
    *(uint4*)&Wt_lo[nrow * D + kc * 8] = vl;
}

// ---------- MFMA GEMM: C[n,128] = (A[n,128] @ B) * dinv[row] ----------
#define TM 64
__global__ __launch_bounds__(256) void k_gemm(const float* __restrict__ A,
                                              const ushort* __restrict__ Bt_hi,
                                              const ushort* __restrict__ Bt_lo,
                                              const float* __restrict__ dinv,
                                              float* __restrict__ C, int n) {
    extern __shared__ char lds[];
    char* Ah = lds;                 // 16KB: 64 rows × 256B
    char* Al = lds + 16 * 1024;     // 16KB
    char* Bh = lds + 32 * 1024;     // 32KB: 128 rows × 256B
    char* Bl = lds + 64 * 1024;     // 32KB

    int tid = threadIdx.x;
    int row0 = blockIdx.x * TM;

#pragma unroll
    for (int it = tid; it < 1024; it += 256) {
        int r = it >> 4, kc = it & 15;
        int gr = row0 + r;
        float f[8] = {0.f, 0.f, 0.f, 0.f, 0.f, 0.f, 0.f, 0.f};
        if (gr < n) {
            const float4* p = (const float4*)(A + (size_t)gr * D + kc * 8);
            float4 a0 = p[0], a1 = p[1];
            f[0] = a0.x; f[1] = a0.y; f[2] = a0.z; f[3] = a0.w;
            f[4] = a1.x; f[5] = a1.y; f[6] = a1.z; f[7] = a1.w;
        }
        uint4 vh, vl;
        cvt8(f, vh, vl);
        *(uint4*)(Ah + swz(r, kc * 16)) = vh;
        *(uint4*)(Al + swz(r, kc * 16)) = vl;
    }
#pragma unroll
    for (int it = tid; it < 2048; it += 256) {
        int r = it >> 4, kc = it & 15;
        uint4 vh = *(const uint4*)(Bt_hi + r * D + kc * 8);
        uint4 vl = *(const uint4*)(Bt_lo + r * D + kc * 8);
        *(uint4*)(Bh + swz(r, kc * 16)) = vh;
        *(uint4*)(Bl + swz(r, kc * 16)) = vl;
    }
    __syncthreads();

    int wave = tid >> 6, lane = tid & 63;
    int li = lane & 15, lg = lane >> 4;
    int arow = wave * 16 + li;

    f32x4 acc[8];
#pragma unroll
    for (int i = 0; i < 8; ++i) acc[i] = (f32x4){0.f, 0.f, 0.f, 0.f};

#pragma unroll
    for (int ks = 0; ks < 4; ++ks) {
        int kb = ks * 64 + lg * 16;
        short8 ah = *(const short8*)(Ah + swz(arow, kb));
        short8 al = *(const short8*)(Al + swz(arow, kb));
#pragma unroll
        for (int nt = 0; nt < 8; ++nt) {
            short8 bh = *(const short8*)(Bh + swz(nt * 16 + li, kb));
            short8 bl = *(const short8*)(Bl + swz(nt * 16 + li, kb));
            acc[nt] = __builtin_amdgcn_mfma_f32_16x16x32_bf16(ah, bh, acc[nt], 0, 0, 0);
            acc[nt] = __builtin_amdgcn_mfma_f32_16x16x32_bf16(al, bh, acc[nt], 0, 0, 0);
            acc[nt] = __builtin_amdgcn_mfma_f32_16x16x32_bf16(ah, bl, acc[nt], 0, 0, 0);
        }
    }

    // C/D layout (m89-verified): col = lane&15, row = (lane>>4)*4 + reg
    int crow0 = row0 + wave * 16 + lg * 4;
#pragma unroll
    for (int j = 0; j < 4; ++j) {
        int gr = crow0 + j;
        if (gr < n) {
            float dv = dinv[gr];
            float* cp = C + (size_t)gr * D + li;
#pragma unroll
            for (int nt = 0; nt < 8; ++nt)
                cp[nt * 16] = acc[nt][j] * dv;
        }
    }
}

// ---------- aggregate + bias + relu, dim-sliced XCD-aware ----------
// h rows pre-scaled by dinv. out[i] = relu(dinv[i]*(sum_N h[r] + h[i]) + b)
// slice s = blockIdx%8 handles dims [16s,16s+16): all blocks of slice s land
// on XCD s (round-robin dispatch), gather set = 3.2MB -> L2-resident.
#define AGG_NODES 64
__global__ __launch_bounds__(256) void k_agg(const float* __restrict__ h,
                                             const float* __restrict__ dinv,
                                             const int* __restrict__ offs,
                                             const int* __restrict__ csr,
                                             const float* __restrict__ bias,
                                             float* __restrict__ out, int n) {
    int slice = blockIdx.x & 7;          // XCD id
    int chunk = blockIdx.x >> 3;
    int node = chunk * AGG_NODES + (threadIdx.x >> 2);
    if (node >= n) return;
    int dim = slice * 16 + (threadIdx.x & 3) * 4;

    float di = dinv[node];
    int s = offs[node], e = offs[node + 1];
    float4 acc = *(const float4*)&h[(size_t)node * D + dim];  // self term
    int p = s;
    for (; p + 4 <= e; p += 4) {
        int r0 = csr[p], r1 = csr[p + 1], r2 = csr[p + 2], r3 = csr[p + 3];
        float4 h0 = *(const float4*)&h[(size_t)r0 * D + dim];
        float4 h1 = *(const float4*)&h[(size_t)r1 * D + dim];
        float4 h2 = *(const float4*)&h[(size_t)r2 * D + dim];
        float4 h3 = *(const float4*)&h[(size_t)r3 * D + dim];
        acc.x += (h0.x + h1.x) + (h2.x + h3.x);
        acc.y += (h0.y + h1.y) + (h2.y + h3.y);
        acc.z += (h0.z + h1.z) + (h2.z + h3.z);
        acc.w += (h0.w + h1.w) + (h2.w + h3.w);
    }
    for (; p < e; ++p) {
        int r = csr[p];
        float4 hv = *(const float4*)&h[(size_t)r * D + dim];
        acc.x += hv.x; acc.y += hv.y; acc.z += hv.z; acc.w += hv.w;
    }
    float4 b4 = *(const float4*)&bias[dim];
    float4 v = make_float4(fmaxf(acc.x * di + b4.x, 0.f),
                           fmaxf(acc.y * di + b4.y, 0.f),
                           fmaxf(acc.z * di + b4.z, 0.f),
                           fmaxf(acc.w * di + b4.w, 0.f));
    *(float4*)&out[(size_t)node * D + dim] = v;
}

// ---------- mean pool per graph (batch sorted) ----------
__global__ __launch_bounds__(128) void k_pool(const float* __restrict__ h,
                                              const int* __restrict__ batch, int n,
                                              float* __restrict__ pooled) {
    int g = blockIdx.x;
    int lo = 0, hi = n;
    while (lo < hi) { int m = (lo + hi) >> 1; if (batch[m] < g) lo = m + 1; else hi = m; }
    int s = lo;
    lo = s; hi = n;
    while (lo < hi) { int m = (lo + hi) >> 1; if (batch[m] < g + 1) lo = m + 1; else hi = m; }
    int e = lo;

    int d = threadIdx.x;
    float a0 = 0.f, a1 = 0.f, a2 = 0.f, a3 = 0.f;
    int i = s;
    for (; i + 4 <= e; i += 4) {
        a0 += h[(size_t)i * D + d];
        a1 += h[(size_t)(i + 1) * D + d];
        a2 += h[(size_t)(i + 2) * D + d];
        a3 += h[(size_t)(i + 3) * D + d];
    }
    for (; i < e; ++i) a0 += h[(size_t)i * D + d];
    float acc = (a0 + a1) + (a2 + a3);
    float cnt = (float)(e - s);
    if (cnt < 1.f) cnt = 1.f;
    pooled[g * D + d] = acc / cnt;
}

// ---------- final linear ----------
__global__ __launch_bounds__(128) void k_final(const float* __restrict__ P,
                                               const float* __restrict__ Wf,
                                               const float* __restrict__ bf,
                                               float* __restrict__ out) {
    __shared__ float pr[D];
    int g = blockIdx.x;
    int c = threadIdx.x;
    pr[c] = P[g * D + c];
    __syncthreads();
    float acc = bf[c];
#pragma unroll 8
    for (int k = 0; k < D; ++k) acc += pr[k] * Wf[k * D + c];
    out[g * D + c] = acc;
}

extern "C" void kernel_launch(void* const* d_in, const int* in_sizes, int n_in,
                              void* d_out, int out_size, void* d_ws, size_t ws_size,
                              hipStream_t stream) {
    const float* x  = (const float*)d_in[0];
    const int*   ei = (const int*)d_in[1];
    const int*   bt = (const int*)d_in[2];
    const float* W1 = (const float*)d_in[3];
    const float* b1 = (const float*)d_in[4];
    const float* W2 = (const float*)d_in[5];
    const float* b2 = (const float*)d_in[6];
    const float* Wf = (const float*)d_in[7];
    const float* bf = (const float*)d_in[8];
    float* out = (float*)d_out;

    int n = in_sizes[2];
    int E = in_sizes[1] / 2;
    int G = out_size / D;

    char* w = (char*)d_ws;
    size_t off = 0;
    auto alloc = [&](size_t bytes) -> void* {
        void* p = w + off;
        off = (off + bytes + 511) & ~(size_t)511;
        return p;
    };
    int*    degcnt = (int*)alloc((size_t)n * 4);
    int*    cursor = (int*)alloc((size_t)n * 4);
    int*    offs   = (int*)alloc((size_t)(n + 1) * 4);
    float*  dinv   = (float*)alloc((size_t)n * 4);
    int*    csr    = (int*)alloc((size_t)E * 4);
    float*  hw     = (float*)alloc((size_t)n * D * 4);
    float*  ha     = (float*)alloc((size_t)n * D * 4);
    float*  pooled = (float*)alloc((size_t)G * D * 4);
    int*    partial= (int*)alloc((size_t)256 * 4);
    ushort* wt1h   = (ushort*)alloc((size_t)D * D * 2);
    ushort* wt1l   = (ushort*)alloc((size_t)D * D * 2);
    ushort* wt2h   = (ushort*)alloc((size_t)D * D * 2);
    ushort* wt2l   = (ushort*)alloc((size_t)D * D * 2);

    hipMemsetAsync(degcnt, 0, (size_t)n * 4, stream);

    int eb = (E + 255) / 256;
    int nb = (n + 255) / 256;
    int sb = (n + 1023) / 1024;
    k_deg<<<eb, 256, 0, stream>>>(ei + E, degcnt, E);
    k_dinv<<<nb, 256, 0, stream>>>(degcnt, dinv, n);
    k_scan_partial<<<sb, 256, 0, stream>>>(degcnt, partial, n);
    k_scan_mid<<<1, 64, 0, stream>>>(partial, sb, offs, n);
    k_scan_final<<<sb, 256, 0, stream>>>(degcnt, partial, offs, cursor, n);
    k_fill<<<eb, 256, 0, stream>>>(ei, cursor, csr, E);

    k_wcvt<<<8, 256, 0, stream>>>(W1, wt1h, wt1l);
    k_wcvt<<<8, 256, 0, stream>>>(W2, wt2h, wt2l);

    int gb = (n + TM - 1) / TM;
    int ab = 8 * ((n + AGG_NODES - 1) / AGG_NODES);
    size_t lds_bytes = 96 * 1024;

    k_gemm<<<gb, 256, lds_bytes, stream>>>(x, wt1h, wt1l, dinv, hw, n);
    k_agg<<<ab, 256, 0, stream>>>(hw, dinv, offs, csr, b1, ha, n);
    k_gemm<<<gb, 256, lds_bytes, stream>>>(ha, wt2h, wt2l, dinv, hw, n);
    k_agg<<<ab, 256, 0, stream>>>(hw, dinv, offs, csr, b2, ha, n);
    k_pool<<<G, 128, 0, stream>>>(ha, bt, n, pooled);
    k_final<<<G, 128, 0, stream>>>(pooled, Wf, bf, out);
}

// Round 5
// 212.163 us; speedup vs baseline: 1.1649x; 1.1649x over previous
//
#include <hip/hip_runtime.h>
#include <hip/hip_bf16.h>

// GCN: h1 = relu(Â (x W1) + b1); h2 = relu(Â (h1 W2) + b2);
// out = meanpool_by_graph(h2) @ Wf + bf
// Â = D^-1/2 (A + I) D^-1/2, deg counted on edge TARGETS + self loop.
//
// GEMMs on MFMA via split-bf16 (3× mfma_f32_16x16x32_bf16, fp32 acc);
// GEMM epilogue pre-scales row i by dinv[i] and writes SLICE-MAJOR layout
// hs[8][n][16]: slice s is a contiguous 3.2MB block -> fits one XCD's 4MB L2.
// k_agg: slice = blockIdx%8 (XCD round-robin), gathers are L2-resident hits;
// output written with nontemporal stores to avoid evicting the hot slice.

#define D 128

typedef __attribute__((ext_vector_type(8))) short short8;
typedef __attribute__((ext_vector_type(4))) float f32x4;

// byte offset into a K-contiguous LDS tile with 256B rows, XOR-swizzled
__device__ __forceinline__ int swz(int row, int kbyte) {
    return row * 256 + (kbyte ^ ((row & 7) << 4));
}

__device__ __forceinline__ void cvt8(const float* f, uint4& vh, uint4& vl) {
    uint h[8], l[8];
#pragma unroll
    for (int j = 0; j < 8; ++j) {
        uint ub = __float_as_uint(f[j]);
        uint hb = ub & 0xffff0000u;           // truncate to bf16-hi
        float r = f[j] - __uint_as_float(hb); // exact residual
        h[j] = hb >> 16;
        l[j] = __float_as_uint(r) >> 16;
    }
    vh = make_uint4(h[0] | (h[1] << 16), h[2] | (h[3] << 16),
                    h[4] | (h[5] << 16), h[6] | (h[7] << 16));
    vl = make_uint4(l[0] | (l[1] << 16), l[2] | (l[3] << 16),
                    l[4] | (l[5] << 16), l[6] | (l[7] << 16));
}

// ---------- degree count ----------
__global__ void k_deg(const int* __restrict__ col, int* __restrict__ cnt, int E) {
    int e = blockIdx.x * blockDim.x + threadIdx.x;
    if (e < E) atomicAdd(&cnt[col[e]], 1);
}

__global__ void k_dinv(const int* __restrict__ cnt, float* __restrict__ dinv, int n) {
    int i = blockIdx.x * blockDim.x + threadIdx.x;
    if (i < n) dinv[i] = 1.0f / sqrtf((float)(cnt[i] + 1));
}

// ---------- two-level exclusive scan over cnt[n] ----------
__global__ __launch_bounds__(256) void k_scan_partial(const int* __restrict__ cnt,
                                                      int* __restrict__ partial, int n) {
    int t = threadIdx.x;
    int base = blockIdx.x * 1024 + t * 4;
    int s = 0;
#pragma unroll
    for (int j = 0; j < 4; ++j) {
        int i = base + j;
        if (i < n) s += cnt[i];
    }
#pragma unroll
    for (int o = 32; o > 0; o >>= 1) s += __shfl_down(s, o, 64);
    __shared__ int ws[4];
    if ((t & 63) == 0) ws[t >> 6] = s;
    __syncthreads();
    if (t == 0) partial[blockIdx.x] = ws[0] + ws[1] + ws[2] + ws[3];
}

__global__ void k_scan_mid(int* __restrict__ partial, int nb,
                           int* __restrict__ offs, int n) {
    if (threadIdx.x == 0 && blockIdx.x == 0) {
        int run = 0;
        for (int i = 0; i < nb; ++i) { int v = partial[i]; partial[i] = run; run += v; }
        offs[n] = run;
    }
}

__global__ __launch_bounds__(256) void k_scan_final(const int* __restrict__ cnt,
                                                    const int* __restrict__ pprefix,
                                                    int* __restrict__ offs,
                                                    int* __restrict__ cursor, int n) {
    int t = threadIdx.x;
    int lane = t & 63;
    int base = blockIdx.x * 1024 + t * 4;
    int v[4];
    int s = 0;
#pragma unroll
    for (int j = 0; j < 4; ++j) {
        int i = base + j;
        v[j] = (i < n) ? cnt[i] : 0;
        s += v[j];
    }
    int inc = s;
#pragma unroll
    for (int o = 1; o < 64; o <<= 1) {
        int u = __shfl_up(inc, o, 64);
        if (lane >= o) inc += u;
    }
    __shared__ int wsum[4];
    if (lane == 63) wsum[t >> 6] = inc;
    __syncthreads();
    int woff = 0;
    int w = t >> 6;
    for (int k = 0; k < w; ++k) woff += wsum[k];
    int excl = woff + (inc - s) + pprefix[blockIdx.x];
#pragma unroll
    for (int j = 0; j < 4; ++j) {
        int i = base + j;
        if (i < n) { offs[i] = excl; cursor[i] = excl; }
        excl += v[j];
    }
}

// ---------- CSR fill ----------
__global__ void k_fill(const int* __restrict__ ei, int* __restrict__ cursor,
                       int* __restrict__ csr, int E) {
    int e = blockIdx.x * blockDim.x + threadIdx.x;
    if (e < E) {
        int r = ei[e];
        int c = ei[E + e];
        int pos = atomicAdd(&cursor[c], 1);
        csr[pos] = r;
    }
}

// ---------- weight convert+transpose: W[k][n] fp32 -> Wt_hi/lo[n][k] bf16 ----------
__global__ __launch_bounds__(256) void k_wcvt(const float* __restrict__ W,
                                              ushort* __restrict__ Wt_hi,
                                              ushort* __restrict__ Wt_lo) {
    int t = blockIdx.x * 256 + threadIdx.x;
    int nrow = t >> 4;
    int kc = t & 15;
    float f[8];
#pragma unroll
    for (int j = 0; j < 8; ++j) f[j] = W[(kc * 8 + j) * D + nrow];
    uint4 vh, vl;
    cvt8(f, vh, vl);
    *(uint4*)&Wt_hi[nrow * D + kc * 8] = vh;
    *(uint4*)&Wt_lo[nrow * D + kc * 8] = vl;
}

// ---------- MFMA GEMM ----------
// C_sliced[nt][row][li] = (A @ B)[row][nt*16+li] * dinv[row]
// A layout: ASLICED ? hs[8][n][16] : row-major [n][128].
#define TM 64
template <bool ASLICED>
__global__ __launch_bounds__(256) void k_gemm(const float* __restrict__ A,
                                              const ushort* __restrict__ Bt_hi,
                                              const ushort* __restrict__ Bt_lo,
                                              const float* __restrict__ dinv,
                                              float* __restrict__ C, int n) {
    extern __shared__ char lds[];
    char* Ah = lds;                 // 16KB: 64 rows × 256B
    char* Al = lds + 16 * 1024;     // 16KB
    char* Bh = lds + 32 * 1024;     // 32KB: 128 rows × 256B
    char* Bl = lds + 64 * 1024;     // 32KB

    int tid = threadIdx.x;
    int row0 = blockIdx.x * TM;

#pragma unroll
    for (int it = tid; it < 1024; it += 256) {
        int r = it >> 4, kc = it & 15;
        int gr = row0 + r;
        float f[8] = {0.f, 0.f, 0.f, 0.f, 0.f, 0.f, 0.f, 0.f};
        if (gr < n) {
            const float4* p;
            if (ASLICED)
                p = (const float4*)(A + ((size_t)(kc >> 1) * n + gr) * 16 + (kc & 1) * 8);
            else
                p = (const float4*)(A + (size_t)gr * D + kc * 8);
            float4 a0 = p[0], a1 = p[1];
            f[0] = a0.x; f[1] = a0.y; f[2] = a0.z; f[3] = a0.w;
            f[4] = a1.x; f[5] = a1.y; f[6] = a1.z; f[7] = a1.w;
        }
        uint4 vh, vl;
        cvt8(f, vh, vl);
        *(uint4*)(Ah + swz(r, kc * 16)) = vh;
        *(uint4*)(Al + swz(r, kc * 16)) = vl;
    }
#pragma unroll
    for (int it = tid; it < 2048; it += 256) {
        int r = it >> 4, kc = it & 15;
        uint4 vh = *(const uint4*)(Bt_hi + r * D + kc * 8);
        uint4 vl = *(const uint4*)(Bt_lo + r * D + kc * 8);
        *(uint4*)(Bh + swz(r, kc * 16)) = vh;
        *(uint4*)(Bl + swz(r, kc * 16)) = vl;
    }
    __syncthreads();

    int wave = tid >> 6, lane = tid & 63;
    int li = lane & 15, lg = lane >> 4;
    int arow = wave * 16 + li;

    f32x4 acc[8];
#pragma unroll
    for (int i = 0; i < 8; ++i) acc[i] = (f32x4){0.f, 0.f, 0.f, 0.f};

#pragma unroll
    for (int ks = 0; ks < 4; ++ks) {
        int kb = ks * 64 + lg * 16;
        short8 ah = *(const short8*)(Ah + swz(arow, kb));
        short8 al = *(const short8*)(Al + swz(arow, kb));
#pragma unroll
        for (int nt = 0; nt < 8; ++nt) {
            short8 bh = *(const short8*)(Bh + swz(nt * 16 + li, kb));
            short8 bl = *(const short8*)(Bl + swz(nt * 16 + li, kb));
            acc[nt] = __builtin_amdgcn_mfma_f32_16x16x32_bf16(ah, bh, acc[nt], 0, 0, 0);
            acc[nt] = __builtin_amdgcn_mfma_f32_16x16x32_bf16(al, bh, acc[nt], 0, 0, 0);
            acc[nt] = __builtin_amdgcn_mfma_f32_16x16x32_bf16(ah, bl, acc[nt], 0, 0, 0);
        }
    }

    // C/D layout (m89-verified): col = lane&15, row = (lane>>4)*4 + reg
    int crow0 = row0 + wave * 16 + lg * 4;
#pragma unroll
    for (int j = 0; j < 4; ++j) {
        int gr = crow0 + j;
        if (gr < n) {
            float dv = dinv[gr];
#pragma unroll
            for (int nt = 0; nt < 8; ++nt)
                C[((size_t)nt * n + gr) * 16 + li] = acc[nt][j] * dv;
        }
    }
}

// ---------- aggregate + bias + relu, slice-major XCD-resident ----------
// hs rows pre-scaled by dinv. outs[s][i][:] = relu(dinv[i]*(sum_N hs[s][r] + hs[s][i]) + b[s*16..])
// slice s = blockIdx%8 -> XCD s (round-robin); slice block = 3.2MB contiguous -> L2 resident.
#define AGG_NB 64
__global__ __launch_bounds__(256) void k_agg(const float* __restrict__ hs,
                                             const float* __restrict__ dinv,
                                             const int* __restrict__ offs,
                                             const int* __restrict__ csr,
                                             const float* __restrict__ bias,
                                             float* __restrict__ outs, int n) {
    int slice = blockIdx.x & 7;
    int chunk = blockIdx.x >> 3;
    int node = chunk * AGG_NB + (threadIdx.x >> 2);
    if (node >= n) return;
    int l4 = (threadIdx.x & 3) * 4;   // float offset within 16-float record

    const float* hbase = hs + (size_t)slice * n * 16;
    float di = dinv[node];
    int s = offs[node], e = offs[node + 1];
    f32x4 acc = *(const f32x4*)(hbase + (size_t)node * 16 + l4);  // self term
    int p = s;
    for (; p + 4 <= e; p += 4) {
        int r0 = csr[p], r1 = csr[p + 1], r2 = csr[p + 2], r3 = csr[p + 3];
        f32x4 h0 = *(const f32x4*)(hbase + (size_t)r0 * 16 + l4);
        f32x4 h1 = *(const f32x4*)(hbase + (size_t)r1 * 16 + l4);
        f32x4 h2 = *(const f32x4*)(hbase + (size_t)r2 * 16 + l4);
        f32x4 h3 = *(const f32x4*)(hbase + (size_t)r3 * 16 + l4);
        acc += (h0 + h1) + (h2 + h3);
    }
    for (; p < e; ++p) {
        int r = csr[p];
        acc += *(const f32x4*)(hbase + (size_t)r * 16 + l4);
    }
    f32x4 b4 = *(const f32x4*)(bias + slice * 16 + l4);
    f32x4 v;
#pragma unroll
    for (int j = 0; j < 4; ++j) v[j] = fmaxf(acc[j] * di + b4[j], 0.f);
    __builtin_nontemporal_store(v, (f32x4*)(outs + ((size_t)slice * n + node) * 16 + l4));
}

// ---------- mean pool per graph (batch sorted; input slice-major) ----------
__global__ __launch_bounds__(128) void k_pool(const float* __restrict__ hs,
                                              const int* __restrict__ batch, int n,
                                              float* __restrict__ pooled) {
    int g = blockIdx.x;
    int lo = 0, hi = n;
    while (lo < hi) { int m = (lo + hi) >> 1; if (batch[m] < g) lo = m + 1; else hi = m; }
    int s = lo;
    lo = s; hi = n;
    while (lo < hi) { int m = (lo + hi) >> 1; if (batch[m] < g + 1) lo = m + 1; else hi = m; }
    int e = lo;

    int d = threadIdx.x;
    const float* base = hs + (size_t)(d >> 4) * n * 16 + (d & 15);
    float a0 = 0.f, a1 = 0.f, a2 = 0.f, a3 = 0.f;
    int i = s;
    for (; i + 4 <= e; i += 4) {
        a0 += base[(size_t)i * 16];
        a1 += base[(size_t)(i + 1) * 16];
        a2 += base[(size_t)(i + 2) * 16];
        a3 += base[(size_t)(i + 3) * 16];
    }
    for (; i < e; ++i) a0 += base[(size_t)i * 16];
    float acc = (a0 + a1) + (a2 + a3);
    float cnt = (float)(e - s);
    if (cnt < 1.f) cnt = 1.f;
    pooled[g * D + d] = acc / cnt;
}

// ---------- final linear ----------
__global__ __launch_bounds__(128) void k_final(const float* __restrict__ P,
                                               const float* __restrict__ Wf,
                                               const float* __restrict__ bf,
                                               float* __restrict__ out) {
    __shared__ float pr[D];
    int g = blockIdx.x;
    int c = threadIdx.x;
    pr[c] = P[g * D + c];
    __syncthreads();
    float acc = bf[c];
#pragma unroll 8
    for (int k = 0; k < D; ++k) acc += pr[k] * Wf[k * D + c];
    out[g * D + c] = acc;
}

extern "C" void kernel_launch(void* const* d_in, const int* in_sizes, int n_in,
                              void* d_out, int out_size, void* d_ws, size_t ws_size,
                              hipStream_t stream) {
    const float* x  = (const float*)d_in[0];
    const int*   ei = (const int*)d_in[1];
    const int*   bt = (const int*)d_in[2];
    const float* W1 = (const float*)d_in[3];
    const float* b1 = (const float*)d_in[4];
    const float* W2 = (const float*)d_in[5];
    const float* b2 = (const float*)d_in[6];
    const float* Wf = (const float*)d_in[7];
    const float* bf = (const float*)d_in[8];
    float* out = (float*)d_out;

    int n = in_sizes[2];
    int E = in_sizes[1] / 2;
    int G = out_size / D;

    char* w = (char*)d_ws;
    size_t off = 0;
    auto alloc = [&](size_t bytes) -> void* {
        void* p = w + off;
        off = (off + bytes + 511) & ~(size_t)511;
        return p;
    };
    int*    degcnt = (int*)alloc((size_t)n * 4);
    int*    cursor = (int*)alloc((size_t)n * 4);
    int*    offs   = (int*)alloc((size_t)(n + 1) * 4);
    float*  dinv   = (float*)alloc((size_t)n * 4);
    int*    csr    = (int*)alloc((size_t)E * 4);
    float*  hw     = (float*)alloc((size_t)n * D * 4);   // slice-major [8][n][16]
    float*  ha     = (float*)alloc((size_t)n * D * 4);   // slice-major [8][n][16]
    float*  pooled = (float*)alloc((size_t)G * D * 4);
    int*    partial= (int*)alloc((size_t)256 * 4);
    ushort* wt1h   = (ushort*)alloc((size_t)D * D * 2);
    ushort* wt1l   = (ushort*)alloc((size_t)D * D * 2);
    ushort* wt2h   = (ushort*)alloc((size_t)D * D * 2);
    ushort* wt2l   = (ushort*)alloc((size_t)D * D * 2);

    hipMemsetAsync(degcnt, 0, (size_t)n * 4, stream);

    int eb = (E + 255) / 256;
    int nb = (n + 255) / 256;
    int sb = (n + 1023) / 1024;
    k_deg<<<eb, 256, 0, stream>>>(ei + E, degcnt, E);
    k_dinv<<<nb, 256, 0, stream>>>(degcnt, dinv, n);
    k_scan_partial<<<sb, 256, 0, stream>>>(degcnt, partial, n);
    k_scan_mid<<<1, 64, 0, stream>>>(partial, sb, offs, n);
    k_scan_final<<<sb, 256, 0, stream>>>(degcnt, partial, offs, cursor, n);
    k_fill<<<eb, 256, 0, stream>>>(ei, cursor, csr, E);

    k_wcvt<<<8, 256, 0, stream>>>(W1, wt1h, wt1l);
    k_wcvt<<<8, 256, 0, stream>>>(W2, wt2h, wt2l);

    int gb = (n + TM - 1) / TM;
    int ab = 8 * ((n + AGG_NB - 1) / AGG_NB);
    size_t lds_bytes = 96 * 1024;

    k_gemm<false><<<gb, 256, lds_bytes, stream>>>(x, wt1h, wt1l, dinv, hw, n);
    k_agg<<<ab, 256, 0, stream>>>(hw, dinv, offs, csr, b1, ha, n);
    k_gemm<true><<<gb, 256, lds_bytes, stream>>>(ha, wt2h, wt2l, dinv, hw, n);
    k_agg<<<ab, 256, 0, stream>>>(hw, dinv, offs, csr, b2, ha, n);
    k_pool<<<G, 128, 0, stream>>>(ha, bt, n, pooled);
    k_final<<<G, 128, 0, stream>>>(pooled, Wf, bf, out);
}

// Round 6
// 211.666 us; speedup vs baseline: 1.1676x; 1.0023x over previous
//
#include <hip/hip_runtime.h>
#include <hip/hip_bf16.h>

// GCN: h1 = relu(Â (x W1) + b1); h2 = relu(Â (h1 W2) + b2);
// out = meanpool_by_graph(h2) @ Wf + bf
// Â = D^-1/2 (A + I) D^-1/2, deg counted on edge TARGETS + self loop.
//
// GEMMs on MFMA via split-bf16 (3× mfma_f32_16x16x32_bf16, fp32 acc);
// GEMM epilogue pre-scales row i by dinv[i] and writes SLICE-MAJOR layout
// hs[8][n][16]: slice s is a contiguous 3.2MB block -> fits one XCD's 4MB L2.
// k_agg: slice = blockIdx%8 (XCD round-robin), gathers are L2-resident hits;
// output written with nontemporal stores to avoid evicting the hot slice.
// degcnt zeroed by our own k_zero (graph-captured hipMemsetAsync fill kernel
// measured 41 us for 200 KB -> replaced).

#define D 128

typedef __attribute__((ext_vector_type(8))) short short8;
typedef __attribute__((ext_vector_type(4))) float f32x4;

// byte offset into a K-contiguous LDS tile with 256B rows, XOR-swizzled
__device__ __forceinline__ int swz(int row, int kbyte) {
    return row * 256 + (kbyte ^ ((row & 7) << 4));
}

__device__ __forceinline__ void cvt8(const float* f, uint4& vh, uint4& vl) {
    uint h[8], l[8];
#pragma unroll
    for (int j = 0; j < 8; ++j) {
        uint ub = __float_as_uint(f[j]);
        uint hb = ub & 0xffff0000u;           // truncate to bf16-hi
        float r = f[j] - __uint_as_float(hb); // exact residual
        h[j] = hb >> 16;
        l[j] = __float_as_uint(r) >> 16;
    }
    vh = make_uint4(h[0] | (h[1] << 16), h[2] | (h[3] << 16),
                    h[4] | (h[5] << 16), h[6] | (h[7] << 16));
    vl = make_uint4(l[0] | (l[1] << 16), l[2] | (l[3] << 16),
                    l[4] | (l[5] << 16), l[6] | (l[7] << 16));
}

// ---------- zero (replaces hipMemsetAsync: captured fill kernel was 41us/200KB) ----------
__global__ void k_zero(int4* __restrict__ p, int n4) {
    int i = blockIdx.x * blockDim.x + threadIdx.x;
    if (i < n4) p[i] = make_int4(0, 0, 0, 0);
}

// ---------- degree count ----------
__global__ void k_deg(const int* __restrict__ col, int* __restrict__ cnt, int E) {
    int e = blockIdx.x * blockDim.x + threadIdx.x;
    if (e < E) atomicAdd(&cnt[col[e]], 1);
}

__global__ void k_dinv(const int* __restrict__ cnt, float* __restrict__ dinv, int n) {
    int i = blockIdx.x * blockDim.x + threadIdx.x;
    if (i < n) dinv[i] = 1.0f / sqrtf((float)(cnt[i] + 1));
}

// ---------- two-level exclusive scan over cnt[n] ----------
__global__ __launch_bounds__(256) void k_scan_partial(const int* __restrict__ cnt,
                                                      int* __restrict__ partial, int n) {
    int t = threadIdx.x;
    int base = blockIdx.x * 1024 + t * 4;
    int s = 0;
#pragma unroll
    for (int j = 0; j < 4; ++j) {
        int i = base + j;
        if (i < n) s += cnt[i];
    }
#pragma unroll
    for (int o = 32; o > 0; o >>= 1) s += __shfl_down(s, o, 64);
    __shared__ int ws[4];
    if ((t & 63) == 0) ws[t >> 6] = s;
    __syncthreads();
    if (t == 0) partial[blockIdx.x] = ws[0] + ws[1] + ws[2] + ws[3];
}

__global__ void k_scan_mid(int* __restrict__ partial, int nb,
                           int* __restrict__ offs, int n) {
    if (threadIdx.x == 0 && blockIdx.x == 0) {
        int run = 0;
        for (int i = 0; i < nb; ++i) { int v = partial[i]; partial[i] = run; run += v; }
        offs[n] = run;
    }
}

__global__ __launch_bounds__(256) void k_scan_final(const int* __restrict__ cnt,
                                                    const int* __restrict__ pprefix,
                                                    int* __restrict__ offs,
                                                    int* __restrict__ cursor, int n) {
    int t = threadIdx.x;
    int lane = t & 63;
    int base = blockIdx.x * 1024 + t * 4;
    int v[4];
    int s = 0;
#pragma unroll
    for (int j = 0; j < 4; ++j) {
        int i = base + j;
        v[j] = (i < n) ? cnt[i] : 0;
        s += v[j];
    }
    int inc = s;
#pragma unroll
    for (int o = 1; o < 64; o <<= 1) {
        int u = __shfl_up(inc, o, 64);
        if (lane >= o) inc += u;
    }
    __shared__ int wsum[4];
    if (lane == 63) wsum[t >> 6] = inc;
    __syncthreads();
    int woff = 0;
    int w = t >> 6;
    for (int k = 0; k < w; ++k) woff += wsum[k];
    int excl = woff + (inc - s) + pprefix[blockIdx.x];
#pragma unroll
    for (int j = 0; j < 4; ++j) {
        int i = base + j;
        if (i < n) { offs[i] = excl; cursor[i] = excl; }
        excl += v[j];
    }
}

// ---------- CSR fill ----------
__global__ void k_fill(const int* __restrict__ ei, int* __restrict__ cursor,
                       int* __restrict__ csr, int E) {
    int e = blockIdx.x * blockDim.x + threadIdx.x;
    if (e < E) {
        int r = ei[e];
        int c = ei[E + e];
        int pos = atomicAdd(&cursor[c], 1);
        csr[pos] = r;
    }
}

// ---------- weight convert+transpose: W[k][n] fp32 -> Wt_hi/lo[n][k] bf16 ----------
__global__ __launch_bounds__(256) void k_wcvt(const float* __restrict__ W,
                                              ushort* __restrict__ Wt_hi,
                                              ushort* __restrict__ Wt_lo) {
    int t = blockIdx.x * 256 + threadIdx.x;
    int nrow = t >> 4;
    int kc = t & 15;
    float f[8];
#pragma unroll
    for (int j = 0; j < 8; ++j) f[j] = W[(kc * 8 + j) * D + nrow];
    uint4 vh, vl;
    cvt8(f, vh, vl);
    *(uint4*)&Wt_hi[nrow * D + kc * 8] = vh;
    *(uint4*)&Wt_lo[nrow * D + kc * 8] = vl;
}

// ---------- MFMA GEMM ----------
// C_sliced[nt][row][li] = (A @ B)[row][nt*16+li] * dinv[row]
// A layout: ASLICED ? hs[8][n][16] : row-major [n][128].
#define TM 64
template <bool ASLICED>
__global__ __launch_bounds__(256) void k_gemm(const float* __restrict__ A,
                                              const ushort* __restrict__ Bt_hi,
                                              const ushort* __restrict__ Bt_lo,
                                              const float* __restrict__ dinv,
                                              float* __restrict__ C, int n) {
    extern __shared__ char lds[];
    char* Ah = lds;                 // 16KB: 64 rows × 256B
    char* Al = lds + 16 * 1024;     // 16KB
    char* Bh = lds + 32 * 1024;     // 32KB: 128 rows × 256B
    char* Bl = lds + 64 * 1024;     // 32KB

    int tid = threadIdx.x;
    int row0 = blockIdx.x * TM;

#pragma unroll
    for (int it = tid; it < 1024; it += 256) {
        int r = it >> 4, kc = it & 15;
        int gr = row0 + r;
        float f[8] = {0.f, 0.f, 0.f, 0.f, 0.f, 0.f, 0.f, 0.f};
        if (gr < n) {
            const float4* p;
            if (ASLICED)
                p = (const float4*)(A + ((size_t)(kc >> 1) * n + gr) * 16 + (kc & 1) * 8);
            else
                p = (const float4*)(A + (size_t)gr * D + kc * 8);
            float4 a0 = p[0], a1 = p[1];
            f[0] = a0.x; f[1] = a0.y; f[2] = a0.z; f[3] = a0.w;
            f[4] = a1.x; f[5] = a1.y; f[6] = a1.z; f[7] = a1.w;
        }
        uint4 vh, vl;
        cvt8(f, vh, vl);
        *(uint4*)(Ah + swz(r, kc * 16)) = vh;
        *(uint4*)(Al + swz(r, kc * 16)) = vl;
    }
#pragma unroll
    for (int it = tid; it < 2048; it += 256) {
        int r = it >> 4, kc = it & 15;
        uint4 vh = *(const uint4*)(Bt_hi + r * D + kc * 8);
        uint4 vl = *(const uint4*)(Bt_lo + r * D + kc * 8);
        *(uint4*)(Bh + swz(r, kc * 16)) = vh;
        *(uint4*)(Bl + swz(r, kc * 16)) = vl;
    }
    __syncthreads();

    int wave = tid >> 6, lane = tid & 63;
    int li = lane & 15, lg = lane >> 4;
    int arow = wave * 16 + li;

    f32x4 acc[8];
#pragma unroll
    for (int i = 0; i < 8; ++i) acc[i] = (f32x4){0.f, 0.f, 0.f, 0.f};

#pragma unroll
    for (int ks = 0; ks < 4; ++ks) {
        int kb = ks * 64 + lg * 16;
        short8 ah = *(const short8*)(Ah + swz(arow, kb));
        short8 al = *(const short8*)(Al + swz(arow, kb));
#pragma unroll
        for (int nt = 0; nt < 8; ++nt) {
            short8 bh = *(const short8*)(Bh + swz(nt * 16 + li, kb));
            short8 bl = *(const short8*)(Bl + swz(nt * 16 + li, kb));
            acc[nt] = __builtin_amdgcn_mfma_f32_16x16x32_bf16(ah, bh, acc[nt], 0, 0, 0);
            acc[nt] = __builtin_amdgcn_mfma_f32_16x16x32_bf16(al, bh, acc[nt], 0, 0, 0);
            acc[nt] = __builtin_amdgcn_mfma_f32_16x16x32_bf16(ah, bl, acc[nt], 0, 0, 0);
        }
    }

    // C/D layout (m89-verified): col = lane&15, row = (lane>>4)*4 + reg
    int crow0 = row0 + wave * 16 + lg * 4;
#pragma unroll
    for (int j = 0; j < 4; ++j) {
        int gr = crow0 + j;
        if (gr < n) {
            float dv = dinv[gr];
#pragma unroll
            for (int nt = 0; nt < 8; ++nt)
                C[((size_t)nt * n + gr) * 16 + li] = acc[nt][j] * dv;
        }
    }
}

// ---------- aggregate + bias + relu, slice-major XCD-resident ----------
#define AGG_NB 64
__global__ __launch_bounds__(256) void k_agg(const float* __restrict__ hs,
                                             const float* __restrict__ dinv,
                                             const int* __restrict__ offs,
                                             const int* __restrict__ csr,
                                             const float* __restrict__ bias,
                                             float* __restrict__ outs, int n) {
    int slice = blockIdx.x & 7;
    int chunk = blockIdx.x >> 3;
    int node = chunk * AGG_NB + (threadIdx.x >> 2);
    if (node >= n) return;
    int l4 = (threadIdx.x & 3) * 4;   // float offset within 16-float record

    const float* hbase = hs + (size_t)slice * n * 16;
    float di = dinv[node];
    int s = offs[node], e = offs[node + 1];
    f32x4 acc = *(const f32x4*)(hbase + (size_t)node * 16 + l4);  // self term
    int p = s;
    for (; p + 4 <= e; p += 4) {
        int r0 = csr[p], r1 = csr[p + 1], r2 = csr[p + 2], r3 = csr[p + 3];
        f32x4 h0 = *(const f32x4*)(hbase + (size_t)r0 * 16 + l4);
        f32x4 h1 = *(const f32x4*)(hbase + (size_t)r1 * 16 + l4);
        f32x4 h2 = *(const f32x4*)(hbase + (size_t)r2 * 16 + l4);
        f32x4 h3 = *(const f32x4*)(hbase + (size_t)r3 * 16 + l4);
        acc += (h0 + h1) + (h2 + h3);
    }
    for (; p < e; ++p) {
        int r = csr[p];
        acc += *(const f32x4*)(hbase + (size_t)r * 16 + l4);
    }
    f32x4 b4 = *(const f32x4*)(bias + slice * 16 + l4);
    f32x4 v;
#pragma unroll
    for (int j = 0; j < 4; ++j) v[j] = fmaxf(acc[j] * di + b4[j], 0.f);
    __builtin_nontemporal_store(v, (f32x4*)(outs + ((size_t)slice * n + node) * 16 + l4));
}

// ---------- mean pool per graph (batch sorted; input slice-major) ----------
__global__ __launch_bounds__(128) void k_pool(const float* __restrict__ hs,
                                              const int* __restrict__ batch, int n,
                                              float* __restrict__ pooled) {
    int g = blockIdx.x;
    int lo = 0, hi = n;
    while (lo < hi) { int m = (lo + hi) >> 1; if (batch[m] < g) lo = m + 1; else hi = m; }
    int s = lo;
    lo = s; hi = n;
    while (lo < hi) { int m = (lo + hi) >> 1; if (batch[m] < g + 1) lo = m + 1; else hi = m; }
    int e = lo;

    int d = threadIdx.x;
    const float* base = hs + (size_t)(d >> 4) * n * 16 + (d & 15);
    float a0 = 0.f, a1 = 0.f, a2 = 0.f, a3 = 0.f;
    int i = s;
    for (; i + 4 <= e; i += 4) {
        a0 += base[(size_t)i * 16];
        a1 += base[(size_t)(i + 1) * 16];
        a2 += base[(size_t)(i + 2) * 16];
        a3 += base[(size_t)(i + 3) * 16];
    }
    for (; i < e; ++i) a0 += base[(size_t)i * 16];
    float acc = (a0 + a1) + (a2 + a3);
    float cnt = (float)(e - s);
    if (cnt < 1.f) cnt = 1.f;
    pooled[g * D + d] = acc / cnt;
}

// ---------- final linear ----------
__global__ __launch_bounds__(128) void k_final(const float* __restrict__ P,
                                               const float* __restrict__ Wf,
                                               const float* __restrict__ bf,
                                               float* __restrict__ out) {
    __shared__ float pr[D];
    int g = blockIdx.x;
    int c = threadIdx.x;
    pr[c] = P[g * D + c];
    __syncthreads();
    float acc = bf[c];
#pragma unroll 8
    for (int k = 0; k < D; ++k) acc += pr[k] * Wf[k * D + c];
    out[g * D + c] = acc;
}

extern "C" void kernel_launch(void* const* d_in, const int* in_sizes, int n_in,
                              void* d_out, int out_size, void* d_ws, size_t ws_size,
                              hipStream_t stream) {
    const float* x  = (const float*)d_in[0];
    const int*   ei = (const int*)d_in[1];
    const int*   bt = (const int*)d_in[2];
    const float* W1 = (const float*)d_in[3];
    const float* b1 = (const float*)d_in[4];
    const float* W2 = (const float*)d_in[5];
    const float* b2 = (const float*)d_in[6];
    const float* Wf = (const float*)d_in[7];
    const float* bf = (const float*)d_in[8];
    float* out = (float*)d_out;

    int n = in_sizes[2];
    int E = in_sizes[1] / 2;
    int G = out_size / D;

    char* w = (char*)d_ws;
    size_t off = 0;
    auto alloc = [&](size_t bytes) -> void* {
        void* p = w + off;
        off = (off + bytes + 511) & ~(size_t)511;
        return p;
    };
    int*    degcnt = (int*)alloc((size_t)n * 4);
    int*    cursor = (int*)alloc((size_t)n * 4);
    int*    offs   = (int*)alloc((size_t)(n + 1) * 4);
    float*  dinv   = (float*)alloc((size_t)n * 4);
    int*    csr    = (int*)alloc((size_t)E * 4);
    float*  hw     = (float*)alloc((size_t)n * D * 4);   // slice-major [8][n][16]
    float*  ha     = (float*)alloc((size_t)n * D * 4);   // slice-major [8][n][16]
    float*  pooled = (float*)alloc((size_t)G * D * 4);
    int*    partial= (int*)alloc((size_t)256 * 4);
    ushort* wt1h   = (ushort*)alloc((size_t)D * D * 2);
    ushort* wt1l   = (ushort*)alloc((size_t)D * D * 2);
    ushort* wt2h   = (ushort*)alloc((size_t)D * D * 2);
    ushort* wt2l   = (ushort*)alloc((size_t)D * D * 2);

    int n4 = (n + 3) / 4;   // degcnt is 512B-aligned; n*4 bytes as int4
    k_zero<<<(n4 + 255) / 256, 256, 0, stream>>>((int4*)degcnt, n4);

    int eb = (E + 255) / 256;
    int nb = (n + 255) / 256;
    int sb = (n + 1023) / 1024;
    k_deg<<<eb, 256, 0, stream>>>(ei + E, degcnt, E);
    k_dinv<<<nb, 256, 0, stream>>>(degcnt, dinv, n);
    k_scan_partial<<<sb, 256, 0, stream>>>(degcnt, partial, n);
    k_scan_mid<<<1, 64, 0, stream>>>(partial, sb, offs, n);
    k_scan_final<<<sb, 256, 0, stream>>>(degcnt, partial, offs, cursor, n);
    k_fill<<<eb, 256, 0, stream>>>(ei, cursor, csr, E);

    k_wcvt<<<8, 256, 0, stream>>>(W1, wt1h, wt1l);
    k_wcvt<<<8, 256, 0, stream>>>(W2, wt2h, wt2l);

    int gb = (n + TM - 1) / TM;
    int ab = 8 * ((n + AGG_NB - 1) / AGG_NB);
    size_t lds_bytes = 96 * 1024;

    k_gemm<false><<<gb, 256, lds_bytes, stream>>>(x, wt1h, wt1l, dinv, hw, n);
    k_agg<<<ab, 256, 0, stream>>>(hw, dinv, offs, csr, b1, ha, n);
    k_gemm<true><<<gb, 256, lds_bytes, stream>>>(ha, wt2h, wt2l, dinv, hw, n);
    k_agg<<<ab, 256, 0, stream>>>(hw, dinv, offs, csr, b2, ha, n);
    k_pool<<<G, 128, 0, stream>>>(ha, bt, n, pooled);
    k_final<<<G, 128, 0, stream>>>(pooled, Wf, bf, out);
}